// Round 5
// baseline (610.823 us; speedup 1.0000x reference)
//
#include <hip/hip_runtime.h>
#include <stdint.h>

#define EPSF 1e-20f

typedef __attribute__((ext_vector_type(4))) int i32x4;
typedef __attribute__((ext_vector_type(16))) int i32x16;
typedef unsigned long long u64;

// ===========================================================================
// Pass 1: fp32 -> packed sign bits via ballot (bit=1 means negative).
// Bit order within each 256-elem chunk is a fixed permutation — identical
// for x and w, so every downstream dot/popcount is invariant.
// 4 chunks per wave with all loads issued up-front (ILP=4).
// ===========================================================================
__global__ __launch_bounds__(256)
void binpack_kernel(const float* __restrict__ x, const float* __restrict__ w,
                    u64* __restrict__ xb, u64* __restrict__ wb, int nxchunk) {
    int wv0 = blockIdx.x * 16 + (threadIdx.x >> 6) * 4;  // first chunk of wave
    int lane = threadIdx.x & 63;
    const float* src; u64* dst; int base;
    if (wv0 < nxchunk) { src = x;  dst = xb; base = wv0; }
    else               { src = w;  dst = wb; base = wv0 - nxchunk; }
    float4 v[4];
#pragma unroll
    for (int j = 0; j < 4; ++j)
        v[j] = ((const float4*)(src + (size_t)(base + j) * 256))[lane];
#pragma unroll
    for (int j = 0; j < 4; ++j) {
        u64 m0 = __ballot(v[j].x < -EPSF);
        u64 m1 = __ballot(v[j].y < -EPSF);
        u64 m2 = __ballot(v[j].z < -EPSF);
        u64 m3 = __ballot(v[j].w < -EPSF);
        if (lane < 4) {
            u64 m = (lane == 0) ? m0 : (lane == 1) ? m1 : (lane == 2) ? m2 : m3;
            dst[(size_t)(base + j) * 4 + lane] = m;
        }
    }
}

// ===========================================================================
// Pass 1b: per-row popcounts px[i] = popc(x row i), pw[j] = popc(w row j).
// One wave per row (64 x u64 = 4096 bits), shuffle-reduce.
// ===========================================================================
__global__ __launch_bounds__(256)
void rowpop_kernel(const u64* __restrict__ xb, const u64* __restrict__ wb,
                   int* __restrict__ px, int* __restrict__ pw, int nxrows) {
    int row = blockIdx.x * 4 + (threadIdx.x >> 6);
    int lane = threadIdx.x & 63;
    const u64* src; int* dst; int r;
    if (row < nxrows) { src = xb; dst = px; r = row; }
    else              { src = wb; dst = pw; r = row - nxrows; }
    int c = __popcll(src[(size_t)r * 64 + lane]);
#pragma unroll
    for (int off = 32; off; off >>= 1) c += __shfl_down(c, off);
    if (lane == 0) dst[r] = c;
}

// ===========================================================================
// Pass 2: packed-bit GEMM with {0,1}-byte expansion (2 ops/nibble — no
// sign-fill ladder): dot(s_x,s_w) = K - 2 px - 2 pw + 4 dot(b_x,b_w).
// Block 256x128, BK=256 bits, 4 waves, wave tile 64x128 (2x4 of 32x32
// v_mfma_i32_32x32x32_i8). Staging: 12 KB packed bits per block-iter via
// global_load_lds (same verified indexing as R4).
// ===========================================================================
#define PM 256
#define PN 128

__device__ __forceinline__ uint32_t expand4_01(uint32_t nib) {
    // 4 sign bits -> 4 bytes of 0x00/0x01 (bit value), 2 VALU ops.
    return __umul24(nib, 0x204081u) & 0x01010101u;
}

__device__ __forceinline__ i32x4 expand16_01(uint32_t q, int hs) {
    uint32_t v = q >> hs;          // lane-half selects bits [16h,16h+16)
    i32x4 r;
    r[0] = (int)expand4_01(v & 15u);
    r[1] = (int)expand4_01((v >> 4) & 15u);
    r[2] = (int)expand4_01((v >> 8) & 15u);
    r[3] = (int)expand4_01((v >> 12) & 15u);
    return r;
}

__global__ __launch_bounds__(256, 2)
void pk_gemm(const char* __restrict__ xb, const char* __restrict__ wb,
             const int* __restrict__ px, const int* __restrict__ pw,
             float* __restrict__ out) {
    __shared__ uint32_t xsp[PM * 8];   // 8 KB packed x tile (256 rows x 256 bits)
    __shared__ uint32_t wsp[PN * 8];   // 4 KB packed w tile

    const int t = threadIdx.x;
    const int lane = t & 63;
    const int wave = t >> 6;
    const int lrow = lane & 31;
    const int half = lane >> 5;
    const int hs = half * 16;
    const int row0 = blockIdx.y * PM;
    const int col0 = blockIdx.x * PN;
    const int wm = wave * 64;

    i32x16 acc[2][4];
#pragma unroll
    for (int r = 0; r < 2; ++r)
#pragma unroll
        for (int c = 0; c < 4; ++c)
#pragma unroll
            for (int e = 0; e < 16; ++e) acc[r][c][e] = 0;

    const int cx0 = t, cx1 = t + 256, cw = t;
    const int rx0 = cx0 >> 1, rx1 = cx1 >> 1, rw = cw >> 1;

    for (int kd = 0; kd < 128; kd += 8) {   // packed-dword offset within row
        __syncthreads();
        __builtin_amdgcn_global_load_lds(
            (const uint32_t*)(xb + (size_t)(row0 + rx0) * 512 + kd * 4 + (cx0 & 1) * 16),
            &xsp[cx0 * 4], 16, 0, 0);
        __builtin_amdgcn_global_load_lds(
            (const uint32_t*)(xb + (size_t)(row0 + rx1) * 512 + kd * 4 + (cx1 & 1) * 16),
            &xsp[cx1 * 4], 16, 0, 0);
        __builtin_amdgcn_global_load_lds(
            (const uint32_t*)(wb + (size_t)(col0 + rw) * 512 + kd * 4 + (cw & 1) * 16),
            &wsp[cw * 4], 16, 0, 0);
        __syncthreads();

#pragma unroll
        for (int hi = 0; hi < 2; ++hi) {
            i32x4 pax[2], pbx[4];
#pragma unroll
            for (int r = 0; r < 2; ++r)
                pax[r] = *(const i32x4*)&xsp[(wm + r * 32 + lrow) * 8 + hi * 4];
#pragma unroll
            for (int c = 0; c < 4; ++c)
                pbx[c] = *(const i32x4*)&wsp[(c * 32 + lrow) * 8 + hi * 4];

#pragma unroll
            for (int s = 0; s < 4; ++s) {
                i32x4 a[2], b[4];
#pragma unroll
                for (int r = 0; r < 2; ++r)
                    a[r] = expand16_01((uint32_t)pax[r][s], hs);
#pragma unroll
                for (int c = 0; c < 4; ++c)
                    b[c] = expand16_01((uint32_t)pbx[c][s], hs);
#pragma unroll
                for (int r = 0; r < 2; ++r)
#pragma unroll
                    for (int c = 0; c < 4; ++c)
                        acc[r][c] = __builtin_amdgcn_mfma_i32_32x32x32_i8(
                            a[r], b[c], acc[r][c], 0, 0, 0);
            }
        }
    }

    // C/D 32x32 layout (verified R2-R4): col = lane&31,
    // row = (e&3) + 8*(e>>2) + 4*(lane>>5)
#pragma unroll
    for (int c = 0; c < 4; ++c) {
        int cc = col0 + c * 32 + lrow;
        int pwv = pw[cc];
#pragma unroll
        for (int r = 0; r < 2; ++r)
#pragma unroll
            for (int e = 0; e < 16; ++e) {
                int rr = row0 + wm + r * 32 + (e & 3) + 8 * (e >> 2) + 4 * half;
                int val = 4096 - 2 * px[rr] - 2 * pwv + 4 * acc[r][c][e];
                out[(size_t)rr * 4096 + cc] = (float)val;
            }
    }
}

// ===========================================================================
extern "C" void kernel_launch(void* const* d_in, const int* in_sizes, int n_in,
                              void* d_out, int out_size, void* d_ws, size_t ws_size,
                              hipStream_t stream) {
    const float* x = (const float*)d_in[0];   // [8192, 4096] fp32
    const float* w = (const float*)d_in[1];   // [4096, 4096] fp32
    float* out = (float*)d_out;

    const int M = 8192, N = 4096, K = 4096;

    // ws layout: xbits 4 MB | wbits 2 MB | px 32 KB | pw 16 KB
    char* xbits = (char*)d_ws;
    char* wbits = xbits + (size_t)M * (K / 8);
    int* px = (int*)(wbits + (size_t)N * (K / 8));
    int* pw = px + M;

    int nxchunk = (M * K) / 256;   // 131072
    int nwchunk = (N * K) / 256;   // 65536
    binpack_kernel<<<(nxchunk + nwchunk) / 16, 256, 0, stream>>>(
        x, w, (u64*)xbits, (u64*)wbits, nxchunk);

    rowpop_kernel<<<(M + N) / 4, 256, 0, stream>>>(
        (const u64*)xbits, (const u64*)wbits, px, pw, M);

    dim3 grid(N / PN, M / PM);     // (32, 32)
    pk_gemm<<<grid, 256, 0, stream>>>(xbits, wbits, px, pw, out);
}